// Round 2
// 162.524 us; speedup vs baseline: 1.0582x; 1.0582x over previous
//
#include <hip/hip_runtime.h>

#define SEQ  4096
#define DMODEL 1024
#define QTOT 16384           // B*S
#define QSCALE 0.18033688011112042f   // (1/sqrt(64)) * log2(e), folded into Q

typedef __bf16 bf16x8 __attribute__((ext_vector_type(8)));
typedef unsigned short u16x8 __attribute__((ext_vector_type(8)));
typedef float f32x4 __attribute__((ext_vector_type(4)));

// ---------- helpers ----------
static __device__ __forceinline__ unsigned short f2bfbits(float f) {
    unsigned int u = __builtin_bit_cast(unsigned int, f);
    unsigned int lsb = (u >> 16) & 1u;
    u += 0x7fffu + lsb;                      // round-to-nearest-even
    return (unsigned short)(u >> 16);
}

static __device__ __forceinline__ bf16x8 ld_frag(const unsigned short* p) {
    uint4 u = *reinterpret_cast<const uint4*>(p);
    return __builtin_bit_cast(bf16x8, u);
}

// ---------- kernel 1: weights -> bf16, pre-swizzled into MFMA fragment order ----------
__global__ void prep_weights(const float* __restrict__ Wq,
                             const float* __restrict__ Wk,
                             const float* __restrict__ Wv,
                             unsigned short* __restrict__ WtS) {
    int o = blockIdx.x * 256 + threadIdx.x;      // 192*1024 total
    int f = o >> 9, q = o & 511;
    int lane = q >> 3, j = q & 7;
    int kc = f / 12, nt = f - kc * 12;
    int n = nt * 16 + (lane & 15);
    int k = kc * 32 + (lane >> 4) * 8 + j;
    float v;
    if (n < 64)       v = Wq[k * 64 + n];
    else if (n < 128) v = Wk[k * 64 + (n - 64)];
    else              v = Wv[k * 64 + (n - 128)];
    WtS[o] = f2bfbits(v);
}

// ---------- kernel 2: fused QKV projection, in-block K-split=4, LDS reduce ----------
// grid 512 x 512 thr (8 waves). Block owns 32 tokens, full K=1024.
// wave w: m = w&1 (16-token M-subtile), kz = w>>1 (K-slice of 256 -> 8 MFMA steps).
// kz>0 waves dump fp32 partials to LDS; kz==0 waves accumulate + bias + bf16 store.
// LDS 75.3 KB -> exactly 2 blocks/CU -> 4 waves/SIMD (2x old proj_split).
// launch_bounds(512,2): do NOT cap VGPR at 128 — the pipelined loop needs
// ~180 regs and a 128 cap would spill to scratch; occupancy is LDS-bound anyway.
__global__ __launch_bounds__(512, 2) void proj_fused(
        const float* __restrict__ emb, const unsigned short* __restrict__ WtS,
        const float* __restrict__ bq, const float* __restrict__ bk,
        const float* __restrict__ bv,
        unsigned short* __restrict__ Qb, unsigned short* __restrict__ Kb,
        unsigned short* __restrict__ VT) {
    // stride 196 floats: 196%32=4 -> rows land on rotating banks, 2-way max (free)
    __shared__ __align__(16) float red[2][3][16][196];   // 75,264 B

    const int tid = threadIdx.x;
    const int w = tid >> 6, lane = tid & 63;
    const int c = lane & 15, qd = lane >> 4;
    const int m = w & 1, kz = w >> 1;
    const int mbase = blockIdx.x * 32 + m * 16;
    const int kbase = kz * 256;

    f32x4 acc[12];
#pragma unroll
    for (int i = 0; i < 12; i++) acc[i] = (f32x4){0.f, 0.f, 0.f, 0.f};

    const float* ap = emb + (size_t)(mbase + c) * DMODEL + kbase + qd * 8;
    const unsigned short* wp = WtS + (size_t)(kbase >> 5) * 6144 + lane * 8;

    float4 e0a = *reinterpret_cast<const float4*>(ap);
    float4 e0b = *reinterpret_cast<const float4*>(ap + 4);
    float4 e1a = *reinterpret_cast<const float4*>(ap + 32);
    float4 e1b = *reinterpret_cast<const float4*>(ap + 36);
    bf16x8 wc[12];
#pragma unroll
    for (int nt = 0; nt < 12; nt++) wc[nt] = ld_frag(wp + nt * 512);

#pragma unroll
    for (int s = 0; s < 8; s++) {
        bf16x8 wn[12];
        if (s < 7) {
#pragma unroll
            for (int nt = 0; nt < 12; nt++)
                wn[nt] = ld_frag(wp + (s + 1) * 6144 + nt * 512);
        } else {
#pragma unroll
            for (int nt = 0; nt < 12; nt++) wn[nt] = wc[nt];
        }
        float4 e2a, e2b;
        if (s < 6) {
            e2a = *reinterpret_cast<const float4*>(ap + (s + 2) * 32);
            e2b = *reinterpret_cast<const float4*>(ap + (s + 2) * 32 + 4);
        } else { e2a = e1a; e2b = e1b; }

        u16x8 at;
        at[0] = f2bfbits(e0a.x); at[1] = f2bfbits(e0a.y);
        at[2] = f2bfbits(e0a.z); at[3] = f2bfbits(e0a.w);
        at[4] = f2bfbits(e0b.x); at[5] = f2bfbits(e0b.y);
        at[6] = f2bfbits(e0b.z); at[7] = f2bfbits(e0b.w);
        bf16x8 af = __builtin_bit_cast(bf16x8, at);

#pragma unroll
        for (int nt = 0; nt < 12; nt++)
            acc[nt] = __builtin_amdgcn_mfma_f32_16x16x32_bf16(af, wc[nt], acc[nt], 0, 0, 0);

        e0a = e1a; e0b = e1b; e1a = e2a; e1b = e2b;
#pragma unroll
        for (int nt = 0; nt < 12; nt++) wc[nt] = wn[nt];
    }

    // ---- in-block K reduction ----
    if (kz > 0) {
#pragma unroll
        for (int nt = 0; nt < 12; nt++)
#pragma unroll
            for (int r = 0; r < 4; r++)
                red[m][kz - 1][qd * 4 + r][nt * 16 + c] = acc[nt][r];
    }
    __syncthreads();
    if (kz == 0) {
#pragma unroll
        for (int nt = 0; nt < 12; nt++) {
            int n = nt * 16 + c;
            float bias = (n < 64) ? bq[n] : (n < 128) ? bk[n - 64] : bv[n - 128];
            float fac = (n < 64) ? QSCALE : 1.0f;
#pragma unroll
            for (int r = 0; r < 4; r++) {
                int row = qd * 4 + r;
                float v = acc[nt][r]
                        + red[m][0][row][n]
                        + red[m][1][row][n]
                        + red[m][2][row][n];
                int token = mbase + row;
                unsigned short bits = f2bfbits((v + bias) * fac);
                if (n < 64)        Qb[(size_t)token * 64 + n] = bits;
                else if (n < 128)  Kb[(size_t)token * 64 + (n - 64)] = bits;
                else {
                    int bb = token >> 12, ss = token & 4095;
                    VT[((size_t)bb * 64 + (n - 128)) * SEQ + ss] = bits;
                }
            }
        }
    }
}

// ---------- kernel 3: barrier-free flash attention ----------
// grid 256 blocks (4b x 64 q-blocks, XCD-pinned by b); 512 thr = 8 waves.
// Block owns 64 q-rows x full t. Wave w owns t-slice [w*512, w*512+512).
// K/V B-fragments loaded DIRECTLY from global (already fragment-shaped).
// End: LDS tree-reduction over the 8 t-slices, then out = acc / l.
__global__ __launch_bounds__(512, 2) void attn(
        const unsigned short* __restrict__ Qb, const unsigned short* __restrict__ Kb,
        const unsigned short* __restrict__ VT, float* __restrict__ out) {
    __shared__ __align__(16) unsigned short Pl[8][64 * 72];  // per-wave P [q][t] (also aliased as reduce buf)
    __shared__ float l_all[8][64];

    const int tid = threadIdx.x;
    const int w = tid >> 6, lane = tid & 63;
    const int c = lane & 15, qd = lane >> 4;
    // XCD pinning: blockIdx%8 = b*2 + (qblk&1)
    const int g3 = blockIdx.x & 7;
    const int b = g3 >> 1;
    const int qblk = ((blockIdx.x >> 3) << 1) | (g3 & 1);
    const int qbase = qblk * 64;
    const int tstart = w * 512;

    // Q A-fragments (same for all 8 waves -> L1 broadcast), pre-scaled by QSCALE
    bf16x8 aq0[4], aq1[4];
#pragma unroll
    for (int qs = 0; qs < 4; qs++) {
        const unsigned short* Qp = Qb + ((size_t)(b << 12) + qbase + qs * 16 + c) * 64 + qd * 8;
        aq0[qs] = ld_frag(Qp);
        aq1[qs] = ld_frag(Qp + 32);
    }

    f32x4 acc[16];                               // [qsub][nt]
#pragma unroll
    for (int i = 0; i < 16; i++) acc[i] = (f32x4){0.f, 0.f, 0.f, 0.f};
    float lsum[4][4];                            // [qsub][r] per-lane partial
#pragma unroll
    for (int qs = 0; qs < 4; qs++)
#pragma unroll
        for (int r = 0; r < 4; r++) lsum[qs][r] = 0.f;

    unsigned short* myP = &Pl[w][0];

#pragma unroll 2
    for (int it = 0; it < 8; it++) {
        const int t0 = tstart + it * 64;
        const unsigned short* Kt = Kb + ((size_t)(b << 12) + t0) * 64;

        // K B-fragments straight from global
        bf16x8 bk0[4], bk1[4];
#pragma unroll
        for (int ts = 0; ts < 4; ts++) {
            bk0[ts] = ld_frag(Kt + (ts * 16 + c) * 64 + qd * 8);
            bk1[ts] = ld_frag(Kt + (ts * 16 + c) * 64 + 32 + qd * 8);
        }

        // scores -> exp2 -> P into per-wave LDS (no barrier)
#pragma unroll
        for (int qs = 0; qs < 4; qs++) {
            f32x4 sc[4];
#pragma unroll
            for (int ts = 0; ts < 4; ts++) {
                f32x4 z = (f32x4){0.f, 0.f, 0.f, 0.f};
                z = __builtin_amdgcn_mfma_f32_16x16x32_bf16(aq0[qs], bk0[ts], z, 0, 0, 0);
                z = __builtin_amdgcn_mfma_f32_16x16x32_bf16(aq1[qs], bk1[ts], z, 0, 0, 0);
                sc[ts] = z;
            }
#pragma unroll
            for (int ts = 0; ts < 4; ts++)
#pragma unroll
                for (int r = 0; r < 4; r++) {
                    float p = __builtin_amdgcn_exp2f(sc[ts][r]);   // scale folded into Q
                    lsum[qs][r] += p;
                    myP[(qs * 16 + qd * 4 + r) * 72 + ts * 16 + c] = f2bfbits(p);
                }
        }

        // V B-fragments straight from global (VT is [b][v][t])
        bf16x8 bv0[4], bv1[4];
#pragma unroll
        for (int nt = 0; nt < 4; nt++) {
            const unsigned short* Vp = VT + (((size_t)b * 64 + nt * 16 + c) << 12) + t0 + qd * 8;
            bv0[nt] = ld_frag(Vp);
            bv1[nt] = ld_frag(Vp + 32);
        }

        // P A-fragments (same-wave LDS readback; compiler inserts lgkmcnt)
#pragma unroll
        for (int qs = 0; qs < 4; qs++) {
            bf16x8 ap0 = ld_frag(&myP[(qs * 16 + c) * 72 + qd * 8]);
            bf16x8 ap1 = ld_frag(&myP[(qs * 16 + c) * 72 + 32 + qd * 8]);
#pragma unroll
            for (int nt = 0; nt < 4; nt++) {
                acc[qs * 4 + nt] = __builtin_amdgcn_mfma_f32_16x16x32_bf16(ap0, bv0[nt], acc[qs * 4 + nt], 0, 0, 0);
                acc[qs * 4 + nt] = __builtin_amdgcn_mfma_f32_16x16x32_bf16(ap1, bv1[nt], acc[qs * 4 + nt], 0, 0, 0);
            }
        }
    }

    // per-wave row-sum reduction across the 16 column lanes
#pragma unroll
    for (int off = 1; off < 16; off <<= 1)
#pragma unroll
        for (int qs = 0; qs < 4; qs++)
#pragma unroll
            for (int r = 0; r < 4; r++) lsum[qs][r] += __shfl_xor(lsum[qs][r], off);
    if (c == 0) {
#pragma unroll
        for (int qs = 0; qs < 4; qs++)
#pragma unroll
            for (int r = 0; r < 4; r++)
                l_all[w][qs * 16 + qd * 4 + r] = lsum[qs][r];
    }

    // tree-reduce acc over 8 waves; reduce buffer aliases Pl (slot = 17408 B)
    float* red = (float*)&Pl[0][0];
    __syncthreads();                              // all main loops + l writes done
    if (w >= 4) {
        float* rp = red + (w - 4) * 4352 + lane * 68;
#pragma unroll
        for (int i = 0; i < 16; i++) *reinterpret_cast<f32x4*>(rp + i * 4) = acc[i];
    }
    __syncthreads();
    if (w < 4) {
        float* rp = red + w * 4352 + lane * 68;
#pragma unroll
        for (int i = 0; i < 16; i++) acc[i] += *reinterpret_cast<const f32x4*>(rp + i * 4);
    }
    __syncthreads();
    if (w == 2 || w == 3) {
        float* rp = red + (w - 2) * 4352 + lane * 68;
#pragma unroll
        for (int i = 0; i < 16; i++) *reinterpret_cast<f32x4*>(rp + i * 4) = acc[i];
    }
    __syncthreads();
    if (w < 2) {
        float* rp = red + w * 4352 + lane * 68;
#pragma unroll
        for (int i = 0; i < 16; i++) acc[i] += *reinterpret_cast<const f32x4*>(rp + i * 4);
    }
    __syncthreads();
    if (w == 1) {
        float* rp = red + lane * 68;
#pragma unroll
        for (int i = 0; i < 16; i++) *reinterpret_cast<f32x4*>(rp + i * 4) = acc[i];
    }
    __syncthreads();
    if (w == 0) {
        float* rp = red + lane * 68;
#pragma unroll
        for (int i = 0; i < 16; i++) acc[i] += *reinterpret_cast<const f32x4*>(rp + i * 4);
#pragma unroll
        for (int qs = 0; qs < 4; qs++)
#pragma unroll
            for (int r = 0; r < 4; r++) {
                int q = qs * 16 + qd * 4 + r;
                float l = 0.f;
#pragma unroll
                for (int ww = 0; ww < 8; ww++) l += l_all[ww][q];
                float inv = 1.0f / l;
                size_t row = (size_t)(b << 12) + qbase + q;
#pragma unroll
                for (int nt = 0; nt < 4; nt++)
                    out[row * 64 + nt * 16 + c] = acc[qs * 4 + nt][r] * inv;
            }
    }
}

// ---------- launch ----------
extern "C" void kernel_launch(void* const* d_in, const int* in_sizes, int n_in,
                              void* d_out, int out_size, void* d_ws, size_t ws_size,
                              hipStream_t stream) {
    const float* emb = (const float*)d_in[0];
    const float* Wq  = (const float*)d_in[1];
    const float* bq  = (const float*)d_in[2];
    const float* Wk  = (const float*)d_in[3];
    const float* bk  = (const float*)d_in[4];
    const float* Wv  = (const float*)d_in[5];
    const float* bv  = (const float*)d_in[6];
    float* out = (float*)d_out;

    unsigned short* ws = (unsigned short*)d_ws;
    unsigned short* WtS = ws;                      // 192*1024
    unsigned short* Qb = ws + 192 * 1024;          // QTOT*64
    unsigned short* Kb = Qb + QTOT * 64;
    unsigned short* VT = Kb + QTOT * 64;           // total 6,684,672 B — always fits

    prep_weights<<<768, 256, 0, stream>>>(Wq, Wk, Wv, WtS);
    proj_fused<<<512, 512, 0, stream>>>(emb, WtS, bq, bk, bv, Qb, Kb, VT);
    attn<<<256, 512, 0, stream>>>(Qb, Kb, VT, out);
}

// Round 3
// 153.727 us; speedup vs baseline: 1.1188x; 1.0572x over previous
//
#include <hip/hip_runtime.h>

#define SEQ  4096
#define DMODEL 1024
#define QTOT 16384           // B*S
#define QSCALE 0.18033688011112042f   // (1/sqrt(64)) * log2(e), folded into Q

typedef __bf16 bf16x8 __attribute__((ext_vector_type(8)));
typedef unsigned short u16x8 __attribute__((ext_vector_type(8)));
typedef float f32x4 __attribute__((ext_vector_type(4)));

// ---------- helpers ----------
static __device__ __forceinline__ unsigned short f2bfbits(float f) {
    unsigned int u = __builtin_bit_cast(unsigned int, f);
    unsigned int lsb = (u >> 16) & 1u;
    u += 0x7fffu + lsb;                      // round-to-nearest-even
    return (unsigned short)(u >> 16);
}

static __device__ __forceinline__ bf16x8 ld_frag(const unsigned short* p) {
    uint4 u = *reinterpret_cast<const uint4*>(p);
    return __builtin_bit_cast(bf16x8, u);
}

// ---------- kernel 1: weights -> bf16, pre-swizzled into MFMA fragment order ----------
__global__ void prep_weights(const float* __restrict__ Wq,
                             const float* __restrict__ Wk,
                             const float* __restrict__ Wv,
                             unsigned short* __restrict__ WtS) {
    int o = blockIdx.x * 256 + threadIdx.x;      // 192*1024 total
    int f = o >> 9, q = o & 511;
    int lane = q >> 3, j = q & 7;
    int kc = f / 12, nt = f - kc * 12;
    int n = nt * 16 + (lane & 15);
    int k = kc * 32 + (lane >> 4) * 8 + j;
    float v;
    if (n < 64)       v = Wq[k * 64 + n];
    else if (n < 128) v = Wk[k * 64 + (n - 64)];
    else              v = Wv[k * 64 + (n - 128)];
    WtS[o] = f2bfbits(v);
}

// ---------- kernel 2: QKV projection, coalesced LDS-staged emb ----------
// grid 512 x 256 thr (4 waves). Block = 32 tokens, N=192, full K (no K-split).
// wave w: m = w&1 (16-token M-subtile), nh = w>>1 (6-of-12 nt slice). acc[6].
// emb is staged through LDS in 4 mega-steps of K=256:
//   - each wave loads ONE CONTIGUOUS 1KB row-chunk per instruction (fixes the
//     4KB-strided 16-segment gather that ran DRAM at ~1 TB/s in proj_fused)
//   - converted to bf16 in-reg, written to an XOR-swizzled LDS tile
//     (off ^= (row&7)<<4, same involution on write and read -> conflict-free
//      ds_read_b128 A-fragments)
//   - next mega's global loads issued BEFORE the 8 MFMA k-steps (T14):
//     HBM latency hides under compute; one barrier per mega-step.
// Weights: per-wave contiguous-1KB global fragment loads, s+1 prefetch pipeline
// (unchanged from verified structure; L1-shared across waves/blocks).
__global__ __launch_bounds__(256) void proj_cs(
        const float* __restrict__ emb, const unsigned short* __restrict__ WtS,
        const float* __restrict__ bq, const float* __restrict__ bk,
        const float* __restrict__ bv,
        unsigned short* __restrict__ Qb, unsigned short* __restrict__ Kb,
        unsigned short* __restrict__ VT) {
    __shared__ __align__(16) unsigned short Et[2][32 * 256];   // 2 x 16 KB

    const int tid = threadIdx.x;
    const int w = tid >> 6, lane = tid & 63;
    const int c = lane & 15, qd = lane >> 4;
    const int m = w & 1, nh = w >> 1;
    const int mbase = blockIdx.x * 32;

    f32x4 acc[6];
#pragma unroll
    for (int i = 0; i < 6; i++) acc[i] = (f32x4){0.f, 0.f, 0.f, 0.f};

    // this wave's weight-fragment base: nt = nh*6 + jj
    const unsigned short* wpB = WtS + nh * 3072 + lane * 8;

    // ---- prologue: stage mega 0 (rows w*8..w*8+7, contiguous 1KB per row) ----
    {
        float4 g[8];
#pragma unroll
        for (int rr = 0; rr < 8; rr++)
            g[rr] = *reinterpret_cast<const float4*>(
                emb + (size_t)(mbase + w * 8 + rr) * DMODEL + lane * 4);
#pragma unroll
        for (int rr = 0; rr < 8; rr++) {
            int row = w * 8 + rr;
            ushort4 p;
            p.x = f2bfbits(g[rr].x); p.y = f2bfbits(g[rr].y);
            p.z = f2bfbits(g[rr].z); p.w = f2bfbits(g[rr].w);
            int off = (lane * 8) ^ ((row & 7) << 4);           // byte off in 512B row
            *reinterpret_cast<ushort4*>(
                reinterpret_cast<char*>(&Et[0][0]) + row * 512 + off) = p;
        }
    }

    // weight fragments for s=0
    bf16x8 wc[6];
#pragma unroll
    for (int jj = 0; jj < 6; jj++) wc[jj] = ld_frag(wpB + jj * 512);

    __syncthreads();

    int cur = 0;
    for (int mega = 0; mega < 4; mega++) {
        // issue next mega's global loads early (in flight during the MFMAs)
        float4 g[8];
        if (mega < 3) {
#pragma unroll
            for (int rr = 0; rr < 8; rr++)
                g[rr] = *reinterpret_cast<const float4*>(
                    emb + (size_t)(mbase + w * 8 + rr) * DMODEL
                        + (mega + 1) * 256 + lane * 4);
        }

        // hoist all 8 A-fragments for this mega (conflict-free swizzled reads)
        const char* Eb = reinterpret_cast<const char*>(&Et[cur][0]);
        bf16x8 aq[8];
#pragma unroll
        for (int ks = 0; ks < 8; ks++) {
            int off = (ks * 64 + qd * 16) ^ ((c & 7) << 4);
            aq[ks] = ld_frag(reinterpret_cast<const unsigned short*>(
                Eb + (m * 16 + c) * 512 + off));
        }

        // 8 K-steps; weight pipeline one step ahead
#pragma unroll
        for (int ks = 0; ks < 8; ks++) {
            int s = mega * 8 + ks;
            bf16x8 wn[6];
            if (s < 31) {
#pragma unroll
                for (int jj = 0; jj < 6; jj++)
                    wn[jj] = ld_frag(wpB + (s + 1) * 6144 + jj * 512);
            } else {
#pragma unroll
                for (int jj = 0; jj < 6; jj++) wn[jj] = wc[jj];
            }
#pragma unroll
            for (int jj = 0; jj < 6; jj++)
                acc[jj] = __builtin_amdgcn_mfma_f32_16x16x32_bf16(aq[ks], wc[jj], acc[jj], 0, 0, 0);
#pragma unroll
            for (int jj = 0; jj < 6; jj++) wc[jj] = wn[jj];
        }

        // convert + write next buffer (vmcnt wait lands here, after compute)
        if (mega < 3) {
#pragma unroll
            for (int rr = 0; rr < 8; rr++) {
                int row = w * 8 + rr;
                ushort4 p;
                p.x = f2bfbits(g[rr].x); p.y = f2bfbits(g[rr].y);
                p.z = f2bfbits(g[rr].z); p.w = f2bfbits(g[rr].w);
                int off = (lane * 8) ^ ((row & 7) << 4);
                *reinterpret_cast<ushort4*>(
                    reinterpret_cast<char*>(&Et[cur ^ 1][0]) + row * 512 + off) = p;
            }
        }
        __syncthreads();
        cur ^= 1;
    }

    // ---- epilogue: bias + scale + bf16 store (proj_direct pattern) ----
#pragma unroll
    for (int jj = 0; jj < 6; jj++) {
        int n = (nh * 6 + jj) * 16 + c;
        float bias = (n < 64) ? bq[n] : (n < 128) ? bk[n - 64] : bv[n - 128];
        float fac = (n < 64) ? QSCALE : 1.0f;
#pragma unroll
        for (int r = 0; r < 4; r++) {
            int token = mbase + m * 16 + qd * 4 + r;
            unsigned short bits = f2bfbits((acc[jj][r] + bias) * fac);
            if (n < 64)        Qb[(size_t)token * 64 + n] = bits;
            else if (n < 128)  Kb[(size_t)token * 64 + (n - 64)] = bits;
            else {
                int bb = token >> 12, ss = token & 4095;
                VT[((size_t)bb * 64 + (n - 128)) * SEQ + ss] = bits;
            }
        }
    }
}

// ---------- kernel 3: barrier-free flash attention ----------
// grid 256 blocks (4b x 64 q-blocks, XCD-pinned by b); 512 thr = 8 waves.
// Block owns 64 q-rows x full t. Wave w owns t-slice [w*512, w*512+512).
// K/V B-fragments loaded DIRECTLY from global (already fragment-shaped).
// End: LDS tree-reduction over the 8 t-slices, then out = acc / l.
__global__ __launch_bounds__(512, 2) void attn(
        const unsigned short* __restrict__ Qb, const unsigned short* __restrict__ Kb,
        const unsigned short* __restrict__ VT, float* __restrict__ out) {
    __shared__ __align__(16) unsigned short Pl[8][64 * 72];  // per-wave P [q][t] (also aliased as reduce buf)
    __shared__ float l_all[8][64];

    const int tid = threadIdx.x;
    const int w = tid >> 6, lane = tid & 63;
    const int c = lane & 15, qd = lane >> 4;
    // XCD pinning: blockIdx%8 = b*2 + (qblk&1)
    const int g3 = blockIdx.x & 7;
    const int b = g3 >> 1;
    const int qblk = ((blockIdx.x >> 3) << 1) | (g3 & 1);
    const int qbase = qblk * 64;
    const int tstart = w * 512;

    // Q A-fragments (same for all 8 waves -> L1 broadcast), pre-scaled by QSCALE
    bf16x8 aq0[4], aq1[4];
#pragma unroll
    for (int qs = 0; qs < 4; qs++) {
        const unsigned short* Qp = Qb + ((size_t)(b << 12) + qbase + qs * 16 + c) * 64 + qd * 8;
        aq0[qs] = ld_frag(Qp);
        aq1[qs] = ld_frag(Qp + 32);
    }

    f32x4 acc[16];                               // [qsub][nt]
#pragma unroll
    for (int i = 0; i < 16; i++) acc[i] = (f32x4){0.f, 0.f, 0.f, 0.f};
    float lsum[4][4];                            // [qsub][r] per-lane partial
#pragma unroll
    for (int qs = 0; qs < 4; qs++)
#pragma unroll
        for (int r = 0; r < 4; r++) lsum[qs][r] = 0.f;

    unsigned short* myP = &Pl[w][0];

#pragma unroll 2
    for (int it = 0; it < 8; it++) {
        const int t0 = tstart + it * 64;
        const unsigned short* Kt = Kb + ((size_t)(b << 12) + t0) * 64;

        // K B-fragments straight from global
        bf16x8 bk0[4], bk1[4];
#pragma unroll
        for (int ts = 0; ts < 4; ts++) {
            bk0[ts] = ld_frag(Kt + (ts * 16 + c) * 64 + qd * 8);
            bk1[ts] = ld_frag(Kt + (ts * 16 + c) * 64 + 32 + qd * 8);
        }

        // scores -> exp2 -> P into per-wave LDS (no barrier)
#pragma unroll
        for (int qs = 0; qs < 4; qs++) {
            f32x4 sc[4];
#pragma unroll
            for (int ts = 0; ts < 4; ts++) {
                f32x4 z = (f32x4){0.f, 0.f, 0.f, 0.f};
                z = __builtin_amdgcn_mfma_f32_16x16x32_bf16(aq0[qs], bk0[ts], z, 0, 0, 0);
                z = __builtin_amdgcn_mfma_f32_16x16x32_bf16(aq1[qs], bk1[ts], z, 0, 0, 0);
                sc[ts] = z;
            }
#pragma unroll
            for (int ts = 0; ts < 4; ts++)
#pragma unroll
                for (int r = 0; r < 4; r++) {
                    float p = __builtin_amdgcn_exp2f(sc[ts][r]);   // scale folded into Q
                    lsum[qs][r] += p;
                    myP[(qs * 16 + qd * 4 + r) * 72 + ts * 16 + c] = f2bfbits(p);
                }
        }

        // V B-fragments straight from global (VT is [b][v][t])
        bf16x8 bv0[4], bv1[4];
#pragma unroll
        for (int nt = 0; nt < 4; nt++) {
            const unsigned short* Vp = VT + (((size_t)b * 64 + nt * 16 + c) << 12) + t0 + qd * 8;
            bv0[nt] = ld_frag(Vp);
            bv1[nt] = ld_frag(Vp + 32);
        }

        // P A-fragments (same-wave LDS readback; compiler inserts lgkmcnt)
#pragma unroll
        for (int qs = 0; qs < 4; qs++) {
            bf16x8 ap0 = ld_frag(&myP[(qs * 16 + c) * 72 + qd * 8]);
            bf16x8 ap1 = ld_frag(&myP[(qs * 16 + c) * 72 + 32 + qd * 8]);
#pragma unroll
            for (int nt = 0; nt < 4; nt++) {
                acc[qs * 4 + nt] = __builtin_amdgcn_mfma_f32_16x16x32_bf16(ap0, bv0[nt], acc[qs * 4 + nt], 0, 0, 0);
                acc[qs * 4 + nt] = __builtin_amdgcn_mfma_f32_16x16x32_bf16(ap1, bv1[nt], acc[qs * 4 + nt], 0, 0, 0);
            }
        }
    }

    // per-wave row-sum reduction across the 16 column lanes
#pragma unroll
    for (int off = 1; off < 16; off <<= 1)
#pragma unroll
        for (int qs = 0; qs < 4; qs++)
#pragma unroll
            for (int r = 0; r < 4; r++) lsum[qs][r] += __shfl_xor(lsum[qs][r], off);
    if (c == 0) {
#pragma unroll
        for (int qs = 0; qs < 4; qs++)
#pragma unroll
            for (int r = 0; r < 4; r++)
                l_all[w][qs * 16 + qd * 4 + r] = lsum[qs][r];
    }

    // tree-reduce acc over 8 waves; reduce buffer aliases Pl (slot = 17408 B)
    float* red = (float*)&Pl[0][0];
    __syncthreads();                              // all main loops + l writes done
    if (w >= 4) {
        float* rp = red + (w - 4) * 4352 + lane * 68;
#pragma unroll
        for (int i = 0; i < 16; i++) *reinterpret_cast<f32x4*>(rp + i * 4) = acc[i];
    }
    __syncthreads();
    if (w < 4) {
        float* rp = red + w * 4352 + lane * 68;
#pragma unroll
        for (int i = 0; i < 16; i++) acc[i] += *reinterpret_cast<const f32x4*>(rp + i * 4);
    }
    __syncthreads();
    if (w == 2 || w == 3) {
        float* rp = red + (w - 2) * 4352 + lane * 68;
#pragma unroll
        for (int i = 0; i < 16; i++) *reinterpret_cast<f32x4*>(rp + i * 4) = acc[i];
    }
    __syncthreads();
    if (w < 2) {
        float* rp = red + w * 4352 + lane * 68;
#pragma unroll
        for (int i = 0; i < 16; i++) acc[i] += *reinterpret_cast<const f32x4*>(rp + i * 4);
    }
    __syncthreads();
    if (w == 1) {
        float* rp = red + lane * 68;
#pragma unroll
        for (int i = 0; i < 16; i++) *reinterpret_cast<f32x4*>(rp + i * 4) = acc[i];
    }
    __syncthreads();
    if (w == 0) {
        float* rp = red + lane * 68;
#pragma unroll
        for (int i = 0; i < 16; i++) acc[i] += *reinterpret_cast<const f32x4*>(rp + i * 4);
#pragma unroll
        for (int qs = 0; qs < 4; qs++)
#pragma unroll
            for (int r = 0; r < 4; r++) {
                int q = qs * 16 + qd * 4 + r;
                float l = 0.f;
#pragma unroll
                for (int ww = 0; ww < 8; ww++) l += l_all[ww][q];
                float inv = 1.0f / l;
                size_t row = (size_t)(b << 12) + qbase + q;
#pragma unroll
                for (int nt = 0; nt < 4; nt++)
                    out[row * 64 + nt * 16 + c] = acc[qs * 4 + nt][r] * inv;
            }
    }
}

// ---------- launch ----------
extern "C" void kernel_launch(void* const* d_in, const int* in_sizes, int n_in,
                              void* d_out, int out_size, void* d_ws, size_t ws_size,
                              hipStream_t stream) {
    const float* emb = (const float*)d_in[0];
    const float* Wq  = (const float*)d_in[1];
    const float* bq  = (const float*)d_in[2];
    const float* Wk  = (const float*)d_in[3];
    const float* bk  = (const float*)d_in[4];
    const float* Wv  = (const float*)d_in[5];
    const float* bv  = (const float*)d_in[6];
    float* out = (float*)d_out;

    unsigned short* ws = (unsigned short*)d_ws;
    unsigned short* WtS = ws;                      // 192*1024
    unsigned short* Qb = ws + 192 * 1024;          // QTOT*64
    unsigned short* Kb = Qb + QTOT * 64;
    unsigned short* VT = Kb + QTOT * 64;           // total 6,684,672 B — always fits

    prep_weights<<<768, 256, 0, stream>>>(Wq, Wk, Wv, WtS);
    proj_cs<<<512, 256, 0, stream>>>(emb, WtS, bq, bk, bv, Qb, Kb, VT);
    attn<<<256, 512, 0, stream>>>(Qb, Kb, VT, out);
}